// Round 15
// baseline (309.219 us; speedup 1.0000x reference)
//
#include <hip/hip_runtime.h>
#include <hip/hip_fp16.h>
#include <hip/hip_cooperative_groups.h>

namespace cg = cooperative_groups;

#define DIM   64
#define TILE  64      // output rows per bucket
#define TSH   6       // log2(TILE)
#define CHUNK 4096    // edges per scatter block
#define ACHUNK 1024   // edges per accum chunk
#define CAPMARGIN 256 // bucket capacity padding (~9 sigma over Binomial sd)
#define NGRID_MAX 512 // cooperative grid cap: 2 blocks/CU x 256 CU

// ---------------- fallback: atomic edge-parallel kernel ----------------
__global__ void __launch_bounds__(256) spmm_edge_kernel(
    const float* __restrict__ vals, const int* __restrict__ src,
    const int* __restrict__ dst, const float* __restrict__ emb,
    float* __restrict__ out, int n_edges)
{
    int e    = blockIdx.x * 4 + (threadIdx.x >> 6);
    int lane = threadIdx.x & 63;
    if (e >= n_edges) return;
    atomicAdd(&out[(size_t)dst[e] * DIM + lane],
              vals[e] * emb[(size_t)src[e] * DIM + lane]);
}

// ---------------- shared-memory layouts ----------------
struct ScatterSM {
    int  lcnt[1024], lscan[1024], gbase[1024], wsum[16];
    int2 stage[CHUNK];
    int  gidx[CHUNK];
};                       // ~61.5 KB -> 2 blocks/CU
struct AccumSM {
    int2 stage[ACHUNK];
    int  rs[TILE], rc[TILE];
};                       // ~8.7 KB
union SMemBig { ScatterSM s; AccumSM a; };

// ---------------- device roles (1024-thread blocks) ----------------
__device__ __forceinline__ void dev_scatter(
    ScatterSM& sm,
    const int* __restrict__ src, const int* __restrict__ dst,
    const float* __restrict__ vals, int n, int base,
    int bucket_base, int cap, int region_base,
    int* __restrict__ bcur, int2* __restrict__ pay)
{
    int tid = threadIdx.x, wid = tid >> 6, lane = tid & 63;
    sm.lcnt[tid] = 0;
    __syncthreads();

    int pk[4], vb[4], bk[4], tk[4]; bool ok[4];
#pragma unroll
    for (int k = 0; k < 4; ++k) {
        int i = base + k * 1024 + tid;
        ok[k] = (i < n);
        if (ok[k]) {
            int s = src[i], d = dst[i];
            vb[k] = __float_as_int(vals[i]);
            bk[k] = d >> TSH;
            pk[k] = (s << TSH) | (d & (TILE - 1));   // src*64 | local-row
            tk[k] = atomicAdd(&sm.lcnt[bk[k]], 1);
        }
    }
    __syncthreads();

    int c = sm.lcnt[tid], s = c;
#pragma unroll
    for (int d = 1; d < 64; d <<= 1) {
        int u = __shfl_up(s, d, 64);
        if (lane >= d) s += u;
    }
    if (lane == 63) sm.wsum[wid] = s;
    __syncthreads();
    if (wid == 0 && lane < 16) {
        int v = sm.wsum[lane], t3 = v;
#pragma unroll
        for (int d = 1; d < 16; d <<= 1) {
            int u = __shfl_up(t3, d, 64);
            if (lane >= d) t3 += u;
        }
        sm.wsum[lane] = t3 - v;
    }
    __syncthreads();
    sm.lscan[tid] = s + sm.wsum[wid];
    sm.gbase[tid] = c ? (region_base + tid * cap +
                         atomicAdd(&bcur[bucket_base + tid], c)) : 0;
    __syncthreads();

#pragma unroll
    for (int k = 0; k < 4; ++k)
        if (ok[k]) {
            int b  = bk[k];
            int sp = sm.lscan[b] - sm.lcnt[b] + tk[k];
            sm.stage[sp] = make_int2(pk[k], vb[k]);
            sm.gidx[sp]  = sm.gbase[b] + tk[k];
        }
    __syncthreads();

    int tot = sm.lscan[1023];
    for (int i = tid; i < tot; i += 1024)
        pay[sm.gidx[i]] = sm.stage[i];
}

__device__ __forceinline__ void dev_cvt(
    const float4* __restrict__ in, __half2* __restrict__ dst,
    long n4, int rank, int nblk)
{
    int t = threadIdx.x;
    for (long i = (long)rank * 1024 + t; i < n4; i += (long)nblk * 1024) {
        float4 f = in[i];
        dst[2 * i]     = __floats2half2_rn(f.x, f.y);
        dst[2 * i + 1] = __floats2half2_rn(f.z, f.w);
    }
}

struct H4 { __half2 a, b; };
__device__ __forceinline__ float4 gld4(const __half* e, int rowelem, int gl) {
    H4 h = *((const H4*)(e + rowelem) + gl);
    float2 fa = __half22float2(h.a), fb = __half22float2(h.b);
    return make_float4(fa.x, fa.y, fb.x, fb.y);
}
__device__ __forceinline__ float4 gld4(const float* e, int rowelem, int gl) {
    return *((const float4*)(e + rowelem) + gl);
}

// 1024-thread accum: counting sort (R8 mechanics), then 64 x 16-lane groups,
// ONE row per group, 4-deep gather chains.
template <typename ET>
__device__ __forceinline__ void dev_accum(
    AccumSM& sm, const int2* __restrict__ pay, int cnt, int start,
    const ET* __restrict__ emb, float* __restrict__ out, int row0, int nrows)
{
    int tid  = threadIdx.x;
    int wid  = tid >> 6;
    int lane = tid & 63;
    int g    = lane >> 4, gl = lane & 15;
    int grp  = wid * 4 + g;          // 0..63, owns row grp

    float4 a = make_float4(0.f, 0.f, 0.f, 0.f);
    int end = start + cnt;

    for (int cb = start; cb < end; cb += ACHUNK) {
        int cn = end - cb; if (cn > ACHUNK) cn = ACHUNK;

        if (tid < TILE) sm.rc[tid] = 0;
        __syncthreads();

        int2 e; int rl = 0, tk = 0; bool ok = (tid < cn);
        if (ok) {
            e  = pay[cb + tid];                    // coalesced, 1 edge/thread
            rl = e.x & (TILE - 1);
            tk = atomicAdd(&sm.rc[rl], 1);
        }
        __syncthreads();

        if (wid == 0) {                            // fully active wave scans
            int c = sm.rc[lane], s = c;
#pragma unroll
            for (int d = 1; d < 64; d <<= 1) {
                int t = __shfl_up(s, d, 64);
                if (lane >= d) s += t;
            }
            sm.rs[lane] = s - c;
        }
        __syncthreads();

        if (ok) sm.stage[sm.rs[rl] + tk] = e;
        __syncthreads();

        int j = sm.rs[grp], jend = j + sm.rc[grp];
        for (; j + 3 < jend; j += 4) {             // 4 chains/group, 256/block
            int2 p0 = sm.stage[j], p1 = sm.stage[j + 1],
                 p2 = sm.stage[j + 2], p3 = sm.stage[j + 3];
            float4 g0 = gld4(emb, p0.x & ~(TILE - 1), gl);
            float4 g1 = gld4(emb, p1.x & ~(TILE - 1), gl);
            float4 g2 = gld4(emb, p2.x & ~(TILE - 1), gl);
            float4 g3 = gld4(emb, p3.x & ~(TILE - 1), gl);
            float v0 = __int_as_float(p0.y), v1 = __int_as_float(p1.y);
            float v2 = __int_as_float(p2.y), v3 = __int_as_float(p3.y);
            a.x += v0 * g0.x; a.y += v0 * g0.y; a.z += v0 * g0.z; a.w += v0 * g0.w;
            a.x += v1 * g1.x; a.y += v1 * g1.y; a.z += v1 * g1.z; a.w += v1 * g1.w;
            a.x += v2 * g2.x; a.y += v2 * g2.y; a.z += v2 * g2.z; a.w += v2 * g2.w;
            a.x += v3 * g3.x; a.y += v3 * g3.y; a.z += v3 * g3.z; a.w += v3 * g3.w;
        }
        for (; j < jend; ++j) {
            int2 p = sm.stage[j];
            float4 gg = gld4(emb, p.x & ~(TILE - 1), gl);
            float v = __int_as_float(p.y);
            a.x += v * gg.x; a.y += v * gg.y; a.z += v * gg.z; a.w += v * gg.w;
        }
        __syncthreads();                           // before reusing rc/stage
    }

    int r = row0 + grp;                            // covers deg-0 rows
    if (r < nrows)
        *((float4*)(out + (size_t)r * DIM) + gl) = a;
}

// ---------------- fused cooperative kernel: zero -> stage -> accum ----------------
template <typename ET>
struct FusedParams {
    const int *src_u, *dst_u; const float *val_u; int n_u, nblk_u;
    const int *src_i, *dst_i; const float *val_i; int n_i, nblk_i;
    int nbu, nbi, cap_u, cap_i;
    int* bcur; int2* pay;
    const float4 *cvtin_u, *cvtin_i;
    __half2 *cvtdst_u, *cvtdst_i;
    long n4u, n4i; int cvt_u_b, cvt_i_b;
    const ET *emb_u, *emb_i;
    float *out_u, *out_i; int nu, ni;
};

// __launch_bounds__(1024, 8): 8 waves/EU caps VGPR at 64 -> 2 blocks/CU
// guaranteed by both VGPR and LDS budgets (123KB <= 160KB). Grid is sized
// from MEASURED occupancy on the host; all loops stride by gridDim.x.
template <typename ET>
__global__ void __launch_bounds__(1024, 8) fused_kernel(FusedParams<ET> p)
{
    __shared__ SMemBig sm;
    cg::grid_group grid = cg::this_grid();
    int bx = blockIdx.x, tid = threadIdx.x;
    int ng = gridDim.x;
    int NB = p.nbu + p.nbi;

    // phase 0: zero bucket counters in-kernel (replaces hipMemsetAsync)
    for (int i = bx * 1024 + tid; i < NB; i += ng * 1024) p.bcur[i] = 0;
    __threadfence();
    grid.sync();

    // phase 1: scatter_u || scatter_i || cvt_u || cvt_i, grid-strided job list
    int njobs = p.nblk_u + p.nblk_i + p.cvt_u_b + p.cvt_i_b;
    for (int job = bx; job < njobs; job += ng) {
        if (job < p.nblk_u)
            dev_scatter(sm.s, p.src_u, p.dst_u, p.val_u, p.n_u, job * CHUNK,
                        0, p.cap_u, 0, p.bcur, p.pay);
        else if (job < p.nblk_u + p.nblk_i)
            dev_scatter(sm.s, p.src_i, p.dst_i, p.val_i, p.n_i,
                        (job - p.nblk_u) * CHUNK,
                        p.nbu, p.cap_i, p.nbu * p.cap_u, p.bcur, p.pay);
        else if (job < p.nblk_u + p.nblk_i + p.cvt_u_b)
            dev_cvt(p.cvtin_u, p.cvtdst_u, p.n4u,
                    job - p.nblk_u - p.nblk_i, p.cvt_u_b);
        else
            dev_cvt(p.cvtin_i, p.cvtdst_i, p.n4i,
                    job - p.nblk_u - p.nblk_i - p.cvt_u_b, p.cvt_i_b);
        __syncthreads();                           // sm reuse across jobs
    }
    __threadfence();                               // pay/cvt visible device-wide
    grid.sync();

    // phase 2: accum buckets, grid-strided
    for (int b = bx; b < NB; b += ng) {
        if (b < p.nbu)
            dev_accum<ET>(sm.a, p.pay, p.bcur[b], b * p.cap_u,
                          p.emb_u, p.out_u, b << TSH, p.nu);
        else {
            int bi = b - p.nbu;
            dev_accum<ET>(sm.a, p.pay, p.bcur[b],
                          p.nbu * p.cap_u + bi * p.cap_i,
                          p.emb_i, p.out_i, bi << TSH, p.ni);
        }
        __syncthreads();                           // sm reuse across buckets
    }
}

// ---------------- non-cooperative fallback kernels (R13-verified path) ------------
__global__ void __launch_bounds__(1024) stage_kernel(
    const int* __restrict__ src_u, const int* __restrict__ dst_u,
    const float* __restrict__ val_u, int n_u, int nblk_u,
    const int* __restrict__ src_i, const int* __restrict__ dst_i,
    const float* __restrict__ val_i, int n_i, int nblk_i,
    int nbu, int cap_u, int cap_i,
    int* __restrict__ bcur, int2* __restrict__ pay,
    const float4* __restrict__ cvtin_u, const float4* __restrict__ cvtin_i,
    __half2* __restrict__ cvtdst_u, __half2* __restrict__ cvtdst_i,
    long n4u, long n4i, int cvt_u_b, int cvt_i_b)
{
    __shared__ ScatterSM sm;
    int bx = blockIdx.x;
    if (bx < nblk_u) {
        dev_scatter(sm, src_u, dst_u, val_u, n_u, bx * CHUNK,
                    0, cap_u, 0, bcur, pay);
    } else if (bx < nblk_u + nblk_i) {
        dev_scatter(sm, src_i, dst_i, val_i, n_i, (bx - nblk_u) * CHUNK,
                    nbu, cap_i, nbu * cap_u, bcur, pay);
    } else if (bx < nblk_u + nblk_i + cvt_u_b) {
        dev_cvt(cvtin_u, cvtdst_u, n4u, bx - nblk_u - nblk_i, cvt_u_b);
    } else {
        dev_cvt(cvtin_i, cvtdst_i, n4i, bx - nblk_u - nblk_i - cvt_u_b, cvt_i_b);
    }
}

template <typename ET>
__global__ void __launch_bounds__(1024) accum_kernel(
    const int2* __restrict__ pay, const int* __restrict__ bcur,
    int nbu, int cap_u, int cap_i,
    const ET* __restrict__ emb_u, const ET* __restrict__ emb_i,
    float* __restrict__ out_u, float* __restrict__ out_i, int nu, int ni)
{
    __shared__ AccumSM sm;
    int b = blockIdx.x;
    if (b < nbu)
        dev_accum<ET>(sm, pay, bcur[b], b * cap_u,
                      emb_u, out_u, b << TSH, nu);
    else {
        int bi = b - nbu;
        dev_accum<ET>(sm, pay, bcur[b], nbu * cap_u + bi * cap_i,
                      emb_i, out_i, bi << TSH, ni);
    }
}

extern "C" void kernel_launch(void* const* d_in, const int* in_sizes, int n_in,
                              void* d_out, int out_size, void* d_ws, size_t ws_size,
                              hipStream_t stream)
{
    const float* users_emb = (const float*)d_in[0];
    const float* items_emb = (const float*)d_in[1];
    const int*   user_src  = (const int*)  d_in[2];
    const int*   user_dst  = (const int*)  d_in[3];
    const float* user_vals = (const float*)d_in[4];
    const int*   item_src  = (const int*)  d_in[5];
    const int*   item_dst  = (const int*)  d_in[6];
    const float* item_vals = (const float*)d_in[7];
    // graph_* inputs (d_in[8..10]) are dead code in the reference.

    const int E_u = in_sizes[2];
    const int E_i = in_sizes[5];
    const int NU  = in_sizes[0] / DIM;
    const int NI  = in_sizes[1] / DIM;

    float* out = (float*)d_out;

    const int NBU = (NU + TILE - 1) / TILE;
    const int NBI = (NI + TILE - 1) / TILE;
    const int NB  = NBU + NBI;

    const int cap_u = (E_u + NBU - 1) / NBU + CAPMARGIN;
    const int cap_i = (E_i + NBI - 1) / NBI + CAPMARGIN;

    size_t hdr_ints    = ((size_t)NB + 1) & ~(size_t)1;
    size_t pay_entries = (size_t)NBU * cap_u + (size_t)NBI * cap_i;
    size_t need_core   = hdr_ints * sizeof(int) + pay_entries * sizeof(int2);
    size_t emb_bytes   = (size_t)(NU + NI) * DIM * sizeof(__half);
    size_t need16      = need_core + emb_bytes;

    if (ws_size < need_core || NU > 65536 || NI > 65536) {
        hipMemsetAsync(d_out, 0, (size_t)out_size * sizeof(float), stream);
        spmm_edge_kernel<<<dim3((E_u + 3) / 4), dim3(256), 0, stream>>>(
            user_vals, user_src, user_dst, users_emb, out, E_u);
        spmm_edge_kernel<<<dim3((E_i + 3) / 4), dim3(256), 0, stream>>>(
            item_vals, item_src, item_dst, items_emb, out + (size_t)NU * DIM, E_i);
        return;
    }

    int*  bcur = (int*)d_ws;                       // NB counters
    int2* pay  = (int2*)((int*)d_ws + hdr_ints);

    const bool use_fp16 = (ws_size >= need16);
    __half* embh = (__half*)((char*)d_ws + need_core);

    const int nblk_u  = (E_u + CHUNK - 1) / CHUNK;
    const int nblk_i  = (E_i + CHUNK - 1) / CHUNK;
    const long n4u    = (long)NU * (DIM / 4);
    const long n4i    = (long)NI * (DIM / 4);

    // ---- measured co-residency: never launch more blocks than fit ----
    int ngrid = 0;
    {
        int occ = 0, ncu = 0;
        hipError_t e1 = use_fp16
            ? hipOccupancyMaxActiveBlocksPerMultiprocessor(
                  &occ, reinterpret_cast<const void*>(&fused_kernel<__half>), 1024, 0)
            : hipOccupancyMaxActiveBlocksPerMultiprocessor(
                  &occ, reinterpret_cast<const void*>(&fused_kernel<float>), 1024, 0);
        hipError_t e2 = hipDeviceGetAttribute(
            &ncu, hipDeviceAttributeMultiprocessorCount, 0);
        if (e1 == hipSuccess && e2 == hipSuccess && occ >= 1 && ncu >= 1) {
            long g = (long)occ * ncu;
            ngrid = (int)(g > NGRID_MAX ? NGRID_MAX : g);
        }
    }

    // cvt blocks sized against the actual grid
    int cvt_total = 0, cvt_u_b = 0, cvt_i_b = 0;
    int gref = (ngrid >= 128) ? ngrid : NGRID_MAX;
    if (use_fp16) {
        cvt_total = gref - ((nblk_u + nblk_i) % gref);
        if (cvt_total < 64) cvt_total += gref;
        cvt_u_b = (int)((long)cvt_total * n4u / (n4u + n4i));
        if (cvt_u_b < 1) cvt_u_b = 1;
        cvt_i_b = cvt_total - cvt_u_b;
        if (cvt_i_b < 1) { cvt_i_b = 1; cvt_u_b = cvt_total - 1; }
    }

    if (ngrid >= 128) {                            // cooperative fused path
        hipError_t cerr;
        if (use_fp16) {
            FusedParams<__half> p = {
                user_src, user_dst, user_vals, E_u, nblk_u,
                item_src, item_dst, item_vals, E_i, nblk_i,
                NBU, NBI, cap_u, cap_i, bcur, pay,
                (const float4*)users_emb, (const float4*)items_emb,
                (__half2*)embh, (__half2*)(embh + (size_t)NU * DIM),
                n4u, n4i, cvt_u_b, cvt_i_b,
                embh, embh + (size_t)NU * DIM,
                out, out + (size_t)NU * DIM, NU, NI };
            void* kargs[] = { (void*)&p };
            cerr = hipLaunchCooperativeKernel(
                reinterpret_cast<const void*>(&fused_kernel<__half>),
                dim3(ngrid), dim3(1024), kargs, 0, stream);
        } else {
            FusedParams<float> p = {
                user_src, user_dst, user_vals, E_u, nblk_u,
                item_src, item_dst, item_vals, E_i, nblk_i,
                NBU, NBI, cap_u, cap_i, bcur, pay,
                (const float4*)users_emb, (const float4*)items_emb,
                (__half2*)nullptr, (__half2*)nullptr,
                0, 0, 0, 0,
                users_emb, items_emb,
                out, out + (size_t)NU * DIM, NU, NI };
            void* kargs[] = { (void*)&p };
            cerr = hipLaunchCooperativeKernel(
                reinterpret_cast<const void*>(&fused_kernel<float>),
                dim3(ngrid), dim3(1024), kargs, 0, stream);
        }
        if (cerr == hipSuccess) return;
    }

    // ---------------- fallback: R13-verified 2-launch path ----------------
    hipMemsetAsync(bcur, 0, (size_t)NB * sizeof(int), stream);

    stage_kernel<<<dim3(nblk_u + nblk_i + cvt_u_b + cvt_i_b), dim3(1024), 0, stream>>>(
        user_src, user_dst, user_vals, E_u, nblk_u,
        item_src, item_dst, item_vals, E_i, nblk_i,
        NBU, cap_u, cap_i, bcur, pay,
        (const float4*)users_emb, (const float4*)items_emb,
        (__half2*)embh, (__half2*)(embh + (size_t)NU * DIM),
        n4u, n4i, cvt_u_b, cvt_i_b);

    if (use_fp16) {
        accum_kernel<__half><<<dim3(NB), dim3(1024), 0, stream>>>(
            pay, bcur, NBU, cap_u, cap_i,
            embh, embh + (size_t)NU * DIM,
            out, out + (size_t)NU * DIM, NU, NI);
    } else {
        accum_kernel<float><<<dim3(NB), dim3(1024), 0, stream>>>(
            pay, bcur, NBU, cap_u, cap_i,
            users_emb, items_emb,
            out, out + (size_t)NU * DIM, NU, NI);
    }
}

// Round 16
// 60.618 us; speedup vs baseline: 5.1011x; 5.1011x over previous
//
#include <hip/hip_runtime.h>
#include <hip/hip_fp16.h>

#define DIM   64
#define TILE  64      // output rows per bucket
#define TSH   6       // log2(TILE)
#define CHUNK 4096    // edges per scatter block
#define ACHUNK 1024   // edges per accum chunk
#define CAPMARGIN 256 // bucket capacity padding (~9 sigma over Binomial sd)

// ---------------- fallback: atomic edge-parallel kernel ----------------
__global__ void __launch_bounds__(256) spmm_edge_kernel(
    const float* __restrict__ vals, const int* __restrict__ src,
    const int* __restrict__ dst, const float* __restrict__ emb,
    float* __restrict__ out, int n_edges)
{
    int e    = blockIdx.x * 4 + (threadIdx.x >> 6);
    int lane = threadIdx.x & 63;
    if (e >= n_edges) return;
    atomicAdd(&out[(size_t)dst[e] * DIM + lane],
              vals[e] * emb[(size_t)src[e] * DIM + lane]);
}

// ---------------- shared-memory layouts ----------------
struct ScatterSM {
    int  lcnt[1024], lscan[1024], gbase[1024], wsum[16];
    int2 stage[CHUNK];
    int  gidx[CHUNK];
};                       // ~61.5 KB -> 2 blocks/CU
struct AccumSM {
    int2 stage[ACHUNK];
    int  rs[TILE], rc[TILE];
};                       // ~8.7 KB

// ---------------- device roles (1024-thread blocks) ----------------
__device__ __forceinline__ void dev_scatter(
    ScatterSM& sm,
    const int* __restrict__ src, const int* __restrict__ dst,
    const float* __restrict__ vals, int n, int base,
    int bucket_base, int cap, int region_base,
    int* __restrict__ bcur, int2* __restrict__ pay)
{
    int tid = threadIdx.x, wid = tid >> 6, lane = tid & 63;
    sm.lcnt[tid] = 0;
    __syncthreads();

    int pk[4], vb[4], bk[4], tk[4]; bool ok[4];
#pragma unroll
    for (int k = 0; k < 4; ++k) {
        int i = base + k * 1024 + tid;
        ok[k] = (i < n);
        if (ok[k]) {
            int s = src[i], d = dst[i];
            vb[k] = __float_as_int(vals[i]);
            bk[k] = d >> TSH;
            pk[k] = (s << TSH) | (d & (TILE - 1));   // src*64 | local-row
            tk[k] = atomicAdd(&sm.lcnt[bk[k]], 1);
        }
    }
    __syncthreads();

    int c = sm.lcnt[tid], s = c;
#pragma unroll
    for (int d = 1; d < 64; d <<= 1) {
        int u = __shfl_up(s, d, 64);
        if (lane >= d) s += u;
    }
    if (lane == 63) sm.wsum[wid] = s;
    __syncthreads();
    if (wid == 0 && lane < 16) {
        int v = sm.wsum[lane], t3 = v;
#pragma unroll
        for (int d = 1; d < 16; d <<= 1) {
            int u = __shfl_up(t3, d, 64);
            if (lane >= d) t3 += u;
        }
        sm.wsum[lane] = t3 - v;
    }
    __syncthreads();
    sm.lscan[tid] = s + sm.wsum[wid];
    sm.gbase[tid] = c ? (region_base + tid * cap +
                         atomicAdd(&bcur[bucket_base + tid], c)) : 0;
    __syncthreads();

#pragma unroll
    for (int k = 0; k < 4; ++k)
        if (ok[k]) {
            int b  = bk[k];
            int sp = sm.lscan[b] - sm.lcnt[b] + tk[k];
            sm.stage[sp] = make_int2(pk[k], vb[k]);
            sm.gidx[sp]  = sm.gbase[b] + tk[k];
        }
    __syncthreads();

    int tot = sm.lscan[1023];
    for (int i = tid; i < tot; i += 1024)
        pay[sm.gidx[i]] = sm.stage[i];
}

__device__ __forceinline__ void dev_cvt(
    const float4* __restrict__ in, __half2* __restrict__ dst,
    long n4, int rank, int nblk)
{
    int t = threadIdx.x;
    for (long i = (long)rank * 1024 + t; i < n4; i += (long)nblk * 1024) {
        float4 f = in[i];
        dst[2 * i]     = __floats2half2_rn(f.x, f.y);
        dst[2 * i + 1] = __floats2half2_rn(f.z, f.w);
    }
}

struct H4 { __half2 a, b; };
__device__ __forceinline__ float4 gld4(const __half* e, int rowelem, int gl) {
    H4 h = *((const H4*)(e + rowelem) + gl);
    float2 fa = __half22float2(h.a), fb = __half22float2(h.b);
    return make_float4(fa.x, fa.y, fb.x, fb.y);
}
__device__ __forceinline__ float4 gld4(const float* e, int rowelem, int gl) {
    return *((const float4*)(e + rowelem) + gl);
}

// 1024-thread accum: counting sort (R8 mechanics), then 64 x 16-lane groups,
// ONE row per group, 4-deep gather chains. 2 blocks/CU (L2-friendly).
template <typename ET>
__device__ __forceinline__ void dev_accum(
    AccumSM& sm, const int2* __restrict__ pay, int cnt, int start,
    const ET* __restrict__ emb, float* __restrict__ out, int row0, int nrows)
{
    int tid  = threadIdx.x;
    int wid  = tid >> 6;
    int lane = tid & 63;
    int g    = lane >> 4, gl = lane & 15;
    int grp  = wid * 4 + g;          // 0..63, owns row grp

    float4 a = make_float4(0.f, 0.f, 0.f, 0.f);
    int end = start + cnt;

    for (int cb = start; cb < end; cb += ACHUNK) {
        int cn = end - cb; if (cn > ACHUNK) cn = ACHUNK;

        if (tid < TILE) sm.rc[tid] = 0;
        __syncthreads();

        int2 e; int rl = 0, tk = 0; bool ok = (tid < cn);
        if (ok) {
            e  = pay[cb + tid];                    // coalesced, 1 edge/thread
            rl = e.x & (TILE - 1);
            tk = atomicAdd(&sm.rc[rl], 1);
        }
        __syncthreads();

        if (wid == 0) {                            // fully active wave scans
            int c = sm.rc[lane], s = c;
#pragma unroll
            for (int d = 1; d < 64; d <<= 1) {
                int t = __shfl_up(s, d, 64);
                if (lane >= d) s += t;
            }
            sm.rs[lane] = s - c;
        }
        __syncthreads();

        if (ok) sm.stage[sm.rs[rl] + tk] = e;
        __syncthreads();

        int j = sm.rs[grp], jend = j + sm.rc[grp];
        for (; j + 3 < jend; j += 4) {             // 4 chains/group, 256/block
            int2 p0 = sm.stage[j], p1 = sm.stage[j + 1],
                 p2 = sm.stage[j + 2], p3 = sm.stage[j + 3];
            float4 g0 = gld4(emb, p0.x & ~(TILE - 1), gl);
            float4 g1 = gld4(emb, p1.x & ~(TILE - 1), gl);
            float4 g2 = gld4(emb, p2.x & ~(TILE - 1), gl);
            float4 g3 = gld4(emb, p3.x & ~(TILE - 1), gl);
            float v0 = __int_as_float(p0.y), v1 = __int_as_float(p1.y);
            float v2 = __int_as_float(p2.y), v3 = __int_as_float(p3.y);
            a.x += v0 * g0.x; a.y += v0 * g0.y; a.z += v0 * g0.z; a.w += v0 * g0.w;
            a.x += v1 * g1.x; a.y += v1 * g1.y; a.z += v1 * g1.z; a.w += v1 * g1.w;
            a.x += v2 * g2.x; a.y += v2 * g2.y; a.z += v2 * g2.z; a.w += v2 * g2.w;
            a.x += v3 * g3.x; a.y += v3 * g3.y; a.z += v3 * g3.z; a.w += v3 * g3.w;
        }
        for (; j < jend; ++j) {
            int2 p = sm.stage[j];
            float4 gg = gld4(emb, p.x & ~(TILE - 1), gl);
            float v = __int_as_float(p.y);
            a.x += v * gg.x; a.y += v * gg.y; a.z += v * gg.z; a.w += v * gg.w;
        }
        __syncthreads();                           // before reusing rc/stage
    }

    int r = row0 + grp;                            // covers deg-0 rows
    if (r < nrows)
        *((float4*)(out + (size_t)r * DIM) + gl) = a;
}

// ---------------- K1: scatter_u || scatter_i || cvt_u || cvt_i (all independent) ---
__global__ void __launch_bounds__(1024) stage_kernel(
    const int* __restrict__ src_u, const int* __restrict__ dst_u,
    const float* __restrict__ val_u, int n_u, int nblk_u,
    const int* __restrict__ src_i, const int* __restrict__ dst_i,
    const float* __restrict__ val_i, int n_i, int nblk_i,
    int nbu, int cap_u, int cap_i,
    int* __restrict__ bcur, int2* __restrict__ pay,
    const float4* __restrict__ cvtin_u, const float4* __restrict__ cvtin_i,
    __half2* __restrict__ cvtdst_u, __half2* __restrict__ cvtdst_i,
    long n4u, long n4i, int cvt_u_b, int cvt_i_b)
{
    __shared__ ScatterSM sm;
    int bx = blockIdx.x;
    if (bx < nblk_u) {
        dev_scatter(sm, src_u, dst_u, val_u, n_u, bx * CHUNK,
                    0, cap_u, 0, bcur, pay);
    } else if (bx < nblk_u + nblk_i) {
        dev_scatter(sm, src_i, dst_i, val_i, n_i, (bx - nblk_u) * CHUNK,
                    nbu, cap_i, nbu * cap_u, bcur, pay);
    } else if (bx < nblk_u + nblk_i + cvt_u_b) {
        dev_cvt(cvtin_u, cvtdst_u, n4u, bx - nblk_u - nblk_i, cvt_u_b);
    } else {
        dev_cvt(cvtin_i, cvtdst_i, n4i, bx - nblk_u - nblk_i - cvt_u_b, cvt_i_b);
    }
}

// ---------------- K2: accum_u || accum_i ----------------
template <typename ET>
__global__ void __launch_bounds__(1024) accum_kernel(
    const int2* __restrict__ pay, const int* __restrict__ bcur,
    int nbu, int cap_u, int cap_i,
    const ET* __restrict__ emb_u, const ET* __restrict__ emb_i,
    float* __restrict__ out_u, float* __restrict__ out_i, int nu, int ni)
{
    __shared__ AccumSM sm;
    int b = blockIdx.x;
    if (b < nbu)
        dev_accum<ET>(sm, pay, bcur[b], b * cap_u,
                      emb_u, out_u, b << TSH, nu);
    else {
        int bi = b - nbu;
        dev_accum<ET>(sm, pay, bcur[b], nbu * cap_u + bi * cap_i,
                      emb_i, out_i, bi << TSH, ni);
    }
}

extern "C" void kernel_launch(void* const* d_in, const int* in_sizes, int n_in,
                              void* d_out, int out_size, void* d_ws, size_t ws_size,
                              hipStream_t stream)
{
    const float* users_emb = (const float*)d_in[0];
    const float* items_emb = (const float*)d_in[1];
    const int*   user_src  = (const int*)  d_in[2];
    const int*   user_dst  = (const int*)  d_in[3];
    const float* user_vals = (const float*)d_in[4];
    const int*   item_src  = (const int*)  d_in[5];
    const int*   item_dst  = (const int*)  d_in[6];
    const float* item_vals = (const float*)d_in[7];
    // graph_* inputs (d_in[8..10]) are dead code in the reference.

    const int E_u = in_sizes[2];
    const int E_i = in_sizes[5];
    const int NU  = in_sizes[0] / DIM;
    const int NI  = in_sizes[1] / DIM;

    float* out = (float*)d_out;

    const int NBU = (NU + TILE - 1) / TILE;
    const int NBI = (NI + TILE - 1) / TILE;
    const int NB  = NBU + NBI;

    const int cap_u = (E_u + NBU - 1) / NBU + CAPMARGIN;
    const int cap_i = (E_i + NBI - 1) / NBI + CAPMARGIN;

    size_t hdr_ints    = ((size_t)NB + 1) & ~(size_t)1;
    size_t pay_entries = (size_t)NBU * cap_u + (size_t)NBI * cap_i;
    size_t need_core   = hdr_ints * sizeof(int) + pay_entries * sizeof(int2);
    size_t emb_bytes   = (size_t)(NU + NI) * DIM * sizeof(__half);
    size_t need16      = need_core + emb_bytes;

    if (ws_size < need_core || NU > 65536 || NI > 65536) {
        hipMemsetAsync(d_out, 0, (size_t)out_size * sizeof(float), stream);
        spmm_edge_kernel<<<dim3((E_u + 3) / 4), dim3(256), 0, stream>>>(
            user_vals, user_src, user_dst, users_emb, out, E_u);
        spmm_edge_kernel<<<dim3((E_i + 3) / 4), dim3(256), 0, stream>>>(
            item_vals, item_src, item_dst, items_emb, out + (size_t)NU * DIM, E_i);
        return;
    }

    int*  bcur = (int*)d_ws;                       // NB counters
    int2* pay  = (int2*)((int*)d_ws + hdr_ints);

    const bool use_fp16 = (ws_size >= need16);
    __half* embh = (__half*)((char*)d_ws + need_core);

    hipMemsetAsync(bcur, 0, (size_t)NB * sizeof(int), stream);

    const int nblk_u  = (E_u + CHUNK - 1) / CHUNK;
    const int nblk_i  = (E_i + CHUNK - 1) / CHUNK;
    const int cvt_u_b = use_fp16 ? 128 : 0;
    const int cvt_i_b = use_fp16 ? 90  : 0;
    const long n4u    = (long)NU * (DIM / 4);
    const long n4i    = (long)NI * (DIM / 4);

    stage_kernel<<<dim3(nblk_u + nblk_i + cvt_u_b + cvt_i_b), dim3(1024), 0, stream>>>(
        user_src, user_dst, user_vals, E_u, nblk_u,
        item_src, item_dst, item_vals, E_i, nblk_i,
        NBU, cap_u, cap_i, bcur, pay,
        (const float4*)users_emb, (const float4*)items_emb,
        (__half2*)embh, (__half2*)(embh + (size_t)NU * DIM),
        n4u, n4i, cvt_u_b, cvt_i_b);

    if (use_fp16) {
        accum_kernel<__half><<<dim3(NB), dim3(1024), 0, stream>>>(
            pay, bcur, NBU, cap_u, cap_i,
            embh, embh + (size_t)NU * DIM,
            out, out + (size_t)NU * DIM, NU, NI);
    } else {
        accum_kernel<float><<<dim3(NB), dim3(1024), 0, stream>>>(
            pay, bcur, NBU, cap_u, cap_i,
            users_emb, items_emb,
            out, out + (size_t)NU * DIM, NU, NI);
    }
}